// Round 2
// baseline (6517.684 us; speedup 1.0000x reference)
//
#include <hip/hip_runtime.h>
#include <stdint.h>
#include <math.h>

typedef unsigned long long u64;
typedef unsigned int u32;

#define CC   512
#define HH   50
#define WW2  76
#define PP   3800      // HH*WW2
#define NB   8
#define NA   34200     // PP*9
#define PRE  6000
#define POST 300
#define MWORDS 96      // u64 words per mask row (94 used, padded)
#define NPAD 8192      // bitonic sort size

// ---------------- workspace layout (bytes) ----------------
// wt     : 9*512*512*4            =  9,437,184   @ 0
// feat   : 8*512*3800*4           = 62,259,200   @ 9,437,184
// boxes  : 8*34200*4*4            =  4,377,600   @ 71,696,384
// scores : 8*34200*4              =  1,094,400   @ 76,073,984
// sb     : 8*6000*4               =    192,000   @ 77,168,384
// bbs    : 8*6000*16              =    768,000   @ 77,360,384
// areas  : 8*6000*4               =    192,000   @ 78,128,384
// mask   : 8*6000*96*8            = 36,864,000   @ 78,320,384

__device__ __forceinline__ u32 skey(float f) {
    u32 u = __float_as_uint(f);
    return (u & 0x80000000u) ? ~u : (u | 0x80000000u);
}

__device__ __forceinline__ float4 anchor_at(int p, int a) {
    const float rv[3] = {0.5f, 1.0f, 2.0f};
    const float sv[3] = {8.0f, 16.0f, 32.0f};
    int ri = a / 3, si = a % 3;
    float s16 = 16.0f * sv[si];
    float hh = s16 * sqrtf(rv[ri]);
    float ww = s16 * sqrtf(1.0f / rv[ri]);
    float bx1 = 8.0f - 0.5f * ww, by1 = 8.0f - 0.5f * hh;
    float bx2 = 8.0f + 0.5f * ww, by2 = 8.0f + 0.5f * hh;
    float sx = (float)((p % WW2) * 16);
    float sy = (float)((p / WW2) * 16);
    return make_float4(sx + bx1, sy + by1, sx + bx2, sy + by2);
}

// ---------------- kernel: transpose conv1 weights to [idx9][ci][co] ----------------
// grid (16,16,9), block (32,8). LDS-tiled.
__global__ void k_wt(const float* __restrict__ w, float* __restrict__ wt) {
    __shared__ float S[32][33];
    int idx = blockIdx.z, co0 = blockIdx.x * 32, ci0 = blockIdx.y * 32;
    int tx = threadIdx.x, ty0 = threadIdx.y;
#pragma unroll
    for (int yy = 0; yy < 32; yy += 8) {
        int ty = ty0 + yy;
        S[ty][tx] = w[((size_t)(co0 + ty) * 512 + ci0 + tx) * 9 + idx];
    }
    __syncthreads();
#pragma unroll
    for (int yy = 0; yy < 32; yy += 8) {
        int ty = ty0 + yy;
        wt[(size_t)idx * 512 * 512 + (size_t)(ci0 + ty) * 512 + co0 + tx] = S[tx][ty];
    }
}

// ---------------- kernel: anchors output ----------------
__global__ void k_anch(float* __restrict__ out3) {
    int t = blockIdx.x * 256 + threadIdx.x;
    if (t >= NA) return;
    int a = t % 9, p = t / 9;
    float4 an = anchor_at(p, a);
    ((float4*)out3)[t] = an;
}

// ---------------- kernel: 3x3 conv 512->512 + bias + relu (implicit GEMM) ----------
// grid (30, 4, 8), block 128.  BM=BN=128, BK=16, 16x8 microkernel,
// register-prefetch double-buffer, ONE barrier per chunk.
__global__ __launch_bounds__(128, 2) void k_conv(
    const float* __restrict__ x, const float* __restrict__ wt,
    const float* __restrict__ bias, float* __restrict__ feat)
{
    const int mt = blockIdx.x, nt = blockIdx.y, img = blockIdx.z;
    const int tid = threadIdx.x;
    __shared__ float As[2][16][128];
    __shared__ float Bs[2][16][128];
    const int m0 = mt * 128, n0 = nt * 128;
    const int p = m0 + tid;          // staging column for A
    const int px = p % 76, py = p / 76;
    const float* xim = x + (size_t)img * CC * PP;
    const int m_t = tid & 7, n_t = tid >> 3;

    float acc[16][8];
#pragma unroll
    for (int i = 0; i < 16; ++i)
#pragma unroll
        for (int j = 0; j < 8; ++j) acc[i][j] = 0.f;

    float ar[16], br[16];

    auto stage = [&](int kk) {
        int idx = kk >> 5;
        int c0 = (kk & 31) << 4;
        int dy = idx / 3 - 1, dx = idx % 3 - 1;
        bool av = (p < PP) && ((unsigned)(py + dy) < 50u) && ((unsigned)(px + dx) < 76u);
        const float* ap = xim + (size_t)c0 * PP + (p + dy * 76 + dx);
        const float* bp = wt + ((size_t)idx << 18) + ((size_t)c0 << 9) + (n0 + tid);
#pragma unroll
        for (int r = 0; r < 16; ++r) {
            ar[r] = av ? ap[(size_t)r * PP] : 0.f;
            br[r] = bp[(size_t)r << 9];
        }
    };

    stage(0);
    for (int kk = 0; kk < 288; ++kk) {
        const int buf = kk & 1;
#pragma unroll
        for (int r = 0; r < 16; ++r) {
            As[buf][r][tid] = ar[r];
            Bs[buf][r][tid] = br[r];
        }
        __syncthreads();
        if (kk + 1 < 288) stage(kk + 1);
#pragma unroll
        for (int k = 0; k < 16; ++k) {
            const float4 a0 = *(const float4*)&As[buf][k][4 * m_t];
            const float4 a1 = *(const float4*)&As[buf][k][32 + 4 * m_t];
            const float4 a2 = *(const float4*)&As[buf][k][64 + 4 * m_t];
            const float4 a3 = *(const float4*)&As[buf][k][96 + 4 * m_t];
            const float4 b0 = *(const float4*)&Bs[buf][k][4 * n_t];
            const float4 b1 = *(const float4*)&Bs[buf][k][64 + 4 * n_t];
            float av8[16] = {a0.x, a0.y, a0.z, a0.w, a1.x, a1.y, a1.z, a1.w,
                             a2.x, a2.y, a2.z, a2.w, a3.x, a3.y, a3.z, a3.w};
            float bv8[8] = {b0.x, b0.y, b0.z, b0.w, b1.x, b1.y, b1.z, b1.w};
#pragma unroll
            for (int i = 0; i < 16; ++i)
#pragma unroll
                for (int j = 0; j < 8; ++j)
                    acc[i][j] = fmaf(av8[i], bv8[j], acc[i][j]);
        }
    }

    // epilogue: bias + relu; thread m(i) = m0+32*(i>>2)+4*m_t+(i&3), n(j) = n0+64*(j>>2)+4*n_t+(j&3)
    float bv[8];
#pragma unroll
    for (int j = 0; j < 8; ++j) bv[j] = bias[n0 + 64 * (j >> 2) + 4 * n_t + (j & 3)];
    float* fimg = feat + (size_t)img * CC * PP;
#pragma unroll
    for (int J = 0; J < 4; ++J) {
        int m = m0 + 32 * J + 4 * m_t;
        if (m >= PP) continue;   // PP%4==0, groups 4-aligned -> no partial vectors
#pragma unroll
        for (int j = 0; j < 8; ++j) {
            int n = n0 + 64 * (j >> 2) + 4 * n_t + (j & 3);
            float4 v;
            v.x = fmaxf(acc[4 * J + 0][j] + bv[j], 0.f);
            v.y = fmaxf(acc[4 * J + 1][j] + bv[j], 0.f);
            v.z = fmaxf(acc[4 * J + 2][j] + bv[j], 0.f);
            v.w = fmaxf(acc[4 * J + 3][j] + bv[j], 0.f);
            *(float4*)&fimg[(size_t)n * PP + m] = v;
        }
    }
}

// ---------------- kernel: fused 1x1 heads + softmax + bbox decode ----------------
// grid (60, 8), block 256. Each block: 64 spatial positions.
__global__ __launch_bounds__(256) void k_heads(
    const float* __restrict__ feat,
    const float* __restrict__ lw, const float* __restrict__ lb,
    const float* __restrict__ sw, const float* __restrict__ sbias,
    const int* __restrict__ imh_p, const int* __restrict__ imw_p,
    float* __restrict__ out0, float* __restrict__ out1,
    float* __restrict__ boxes, float* __restrict__ scores)
{
    int img = blockIdx.y;
    int p0 = blockIdx.x * 64;
    int tid = threadIdx.x;
    int pl = tid & 63, cg = tid >> 6;
    __shared__ float Fs[32][65];
    __shared__ float Wsh[54][32];
    __shared__ float O[54][64];
    float acc[14];
#pragma unroll
    for (int j = 0; j < 14; ++j) acc[j] = 0.f;
    const float* fimg = feat + (size_t)img * CC * PP;

    for (int c0 = 0; c0 < CC; c0 += 32) {
        __syncthreads();
#pragma unroll
        for (int i = 0; i < 8; ++i) {
            int k = cg * 8 + i;
            int p = p0 + pl;
            Fs[k][pl] = (p < PP) ? fimg[(size_t)(c0 + k) * PP + p] : 0.f;
        }
        for (int e = tid; e < 54 * 32; e += 256) {
            int c = e >> 5, k = e & 31;
            Wsh[c][k] = (c < 36) ? lw[c * CC + c0 + k] : sw[(c - 36) * CC + c0 + k];
        }
        __syncthreads();
#pragma unroll
        for (int k = 0; k < 32; ++k) {
            float f = Fs[k][pl];
#pragma unroll
            for (int j = 0; j < 14; ++j) {
                int c = cg * 14 + j;
                if (c < 54) acc[j] = fmaf(Wsh[c][k], f, acc[j]);
            }
        }
    }
    __syncthreads();
#pragma unroll
    for (int j = 0; j < 14; ++j) {
        int c = cg * 14 + j;
        if (c < 54) O[c][pl] = acc[j] + (c < 36 ? lb[c] : sbias[c - 36]);
    }
    __syncthreads();

    float fimh = (float)(*imh_p), fimw = (float)(*imw_p);
    for (int e = tid; e < 576; e += 256) {
        int pl2 = e / 9, a = e % 9;
        int p = p0 + pl2;
        if (p >= PP) continue;
        float l0 = O[a * 4 + 0][pl2], l1 = O[a * 4 + 1][pl2];
        float l2v = O[a * 4 + 2][pl2], l3 = O[a * 4 + 3][pl2];
        float s0 = O[36 + a * 2][pl2], s1 = O[36 + a * 2 + 1][pl2];
        size_t ai = (size_t)img * NA + (size_t)p * 9 + a;
        *(float4*)&out0[ai * 4] = make_float4(l0, l1, l2v, l3);
        *(float2*)&out1[ai * 2] = make_float2(s0, s1);
        float mx = fmaxf(s0, s1);
        float e0 = expf(s0 - mx), e1 = expf(s1 - mx);
        float fg = e1 / (e0 + e1);
        float4 an = anchor_at(p, a);
        float aw = an.z - an.x, ah = an.w - an.y;
        float ax = an.x + 0.5f * aw, ay = an.y + 0.5f * ah;
        float cx = l0 * aw + ax;
        float cy = l1 * ah + ay;
        float wb = expf(l2v) * aw, hb = expf(l3) * ah;
        float x1 = cx - 0.5f * wb, y1 = cy - 0.5f * hb;
        float x2 = cx + 0.5f * wb, y2 = cy + 0.5f * hb;
        x1 = fminf(fmaxf(x1, 0.f), fimw);
        x2 = fminf(fmaxf(x2, 0.f), fimw);
        y1 = fminf(fmaxf(y1, 0.f), fimh);
        y2 = fminf(fmaxf(y2, 0.f), fimh);
        bool valid = ((x2 - x1) >= 16.0f) && ((y2 - y1) >= 16.0f);
        ((float4*)boxes)[ai] = make_float4(x1, y1, x2, y2);
        scores[ai] = valid ? fg : -INFINITY;
    }
}

// ---------------- kernel: per-image top-6000 select + stable sort (LDS) ----------
// grid 8, block 1024. Radix-threshold (4x8-bit) then LDS bitonic sort.
// dynamic LDS: arr (NPAD u64) + hist (256 u32)
__global__ __launch_bounds__(1024) void k_select(
    const float* __restrict__ scores, const float4* __restrict__ boxes,
    float* __restrict__ sb, float4* __restrict__ bbs, float* __restrict__ areas)
{
    extern __shared__ u64 dyn[];
    u64* arr = dyn;                       // NPAD u64 = 64KB
    u32* hist = (u32*)(dyn + NPAD);       // 256 u32
    __shared__ u32 s_pref, s_rem, s_cnt;
    int img = blockIdx.x;
    int tid = threadIdx.x;
    const float* sc = scores + (size_t)img * NA;
    if (tid == 0) { s_pref = 0; s_rem = PRE; }
    u32 pmask = 0;
    for (int sh = 24; sh >= 0; sh -= 8) {
        for (int i = tid; i < 256; i += 1024) hist[i] = 0;
        __syncthreads();
        u32 pref = s_pref;
        for (int e = tid; e < NA; e += 1024) {
            u32 k = skey(sc[e]);
            if ((k & pmask) == pref) atomicAdd(&hist[(k >> sh) & 255], 1);
        }
        __syncthreads();
        if (tid == 0) {
            u32 c = 0; u32 rem = s_rem; u32 pv = s_pref;
            for (int d = 255; d >= 0; --d) {
                u32 h = hist[d];
                if (c + h >= rem) { s_pref = pv | ((u32)d << sh); s_rem = rem - c; break; }
                c += h;
            }
        }
        __syncthreads();
        pmask |= (0xFFu << sh);
    }
    u32 T = s_pref;
    if (tid == 0) s_cnt = 0;
    __syncthreads();
    for (int e = tid; e < NA; e += 1024) {
        u32 k = skey(sc[e]);
        if (k >= T) {
            u32 pos = atomicAdd(&s_cnt, 1);
            if (pos < NPAD) arr[pos] = ((u64)k << 32) | (u64)(~(u32)e);
        }
    }
    __syncthreads();
    u32 n = s_cnt; if (n > NPAD) n = NPAD;
    for (u32 t2 = n + tid; t2 < NPAD; t2 += 1024) arr[t2] = 0;
    // bitonic sort descending by (key, ~idx)
    for (u32 size = 2; size <= NPAD; size <<= 1) {
        for (u32 stride = size >> 1; stride > 0; stride >>= 1) {
            __syncthreads();
            for (u32 t2 = tid; t2 < NPAD / 2; t2 += 1024) {
                u32 i = 2 * t2 - (t2 & (stride - 1));
                u32 j = i + stride;
                u64 a = arr[i], b = arr[j];
                bool desc = ((i & size) == 0);
                if (desc ? (a < b) : (a > b)) { arr[i] = b; arr[j] = a; }
            }
        }
    }
    __syncthreads();
    for (int t2 = tid; t2 < PRE; t2 += 1024) {
        u64 v = arr[t2];
        u32 e = ~(u32)v;
        float s = sc[e];
        float4 bx = boxes[(size_t)img * NA + e];
        sb[img * PRE + t2] = s;
        bbs[img * PRE + t2] = bx;
        areas[img * PRE + t2] = (bx.z - bx.x) * (bx.w - bx.y);
    }
}

// ---------------- kernel: IoU suppression bitmask ----------------
// grid (94, 24, 8), block 256 = 64 i x 4 j-words. LDS-staged j boxes.
__global__ __launch_bounds__(256) void k_mask(
    const float4* __restrict__ bbs, const float* __restrict__ areas,
    u64* __restrict__ mask)
{
    int img = blockIdx.z, iT = blockIdx.x, jT = blockIdx.y;
    int tid = threadIdx.x;
    __shared__ float4 jb[256];
    __shared__ float ja[256];
    int jj = jT * 256 + tid;
    jb[tid] = (jj < PRE) ? bbs[(size_t)img * PRE + jj] : make_float4(0, 0, 0, 0);
    ja[tid] = (jj < PRE) ? areas[img * PRE + jj] : 0.f;
    __syncthreads();
    int i = iT * 64 + (tid & 63);
    int jw = jT * 4 + (tid >> 6);
    if (i >= PRE) return;
    float4 bi = bbs[(size_t)img * PRE + i];
    float ai = areas[img * PRE + i];
    int j0 = (tid >> 6) * 64;
    u64 m = 0;
#pragma unroll 4
    for (int b = 0; b < 64; ++b) {
        int j = jw * 64 + b;
        if (j >= PRE) break;
        if (j > i) {
            float4 bj = jb[j0 + b];
            float xx1 = fmaxf(bi.x, bj.x), yy1 = fmaxf(bi.y, bj.y);
            float xx2 = fminf(bi.z, bj.z), yy2 = fminf(bi.w, bj.w);
            float iw = fmaxf(xx2 - xx1, 0.f), ih2 = fmaxf(yy2 - yy1, 0.f);
            float inter = iw * ih2;
            float iou = inter / (ai + ja[j0 + b] - inter + 1e-9f);
            if (iou > 0.7f) m |= (1ull << b);
        }
    }
    mask[((size_t)img * PRE + i) * MWORDS + jw] = m;
}

// ---------------- kernel: sequential NMS scan + top-300 emit ----------------
// grid 8, block 64 (single wave).
__global__ __launch_bounds__(64) void k_scan(
    const float* __restrict__ sb, const float4* __restrict__ bbs,
    const u64* __restrict__ mask, float* __restrict__ out2)
{
    int img = blockIdx.x;
    int lane = threadIdx.x;
    __shared__ u64 keep[96];
    __shared__ int list[POST];
    __shared__ int s_n;
    for (int w = lane; w < 96; w += 64) {
        u64 bits = 0;
        for (int b = 0; b < 64; ++b) {
            int j = w * 64 + b;
            if (j < PRE) {
                float s = sb[img * PRE + j];
                if (isfinite(s)) bits |= (1ull << b);
            }
        }
        keep[w] = bits;
    }
    __syncthreads();
    for (int w = 0; w < 94; ++w) {
        u64 cur = keep[w];
        while (cur) {
            int b = __builtin_ctzll(cur);
            int i = w * 64 + b;
            const u64* mrow = mask + ((size_t)img * PRE + i) * MWORDS;
            if (lane < 47) {
                ulonglong2 mv = *(const ulonglong2*)&mrow[2 * lane];
                keep[2 * lane]     &= ~mv.x;
                keep[2 * lane + 1] &= ~mv.y;
            }
            __syncthreads();
            u64 kw = keep[w];
            cur = (b >= 63) ? 0ull : ((kw >> (b + 1)) << (b + 1));
        }
    }
    __syncthreads();
    if (lane == 0) {
        int n = 0;
        for (int w = 0; w < 94 && n < POST; ++w) {
            u64 bits = keep[w];
            while (bits && n < POST) {
                int b = __builtin_ctzll(bits);
                bits &= bits - 1;
                list[n++] = w * 64 + b;
            }
        }
        s_n = n;
    }
    __syncthreads();
    int n = s_n;
    for (int e = lane; e < POST; e += 64) {
        float4 bx = (e < n) ? bbs[(size_t)img * PRE + list[e]] : make_float4(0, 0, 0, 0);
        *(float4*)&out2[((size_t)img * POST + e) * 4] = bx;
    }
}

extern "C" void kernel_launch(void* const* d_in, const int* in_sizes, int n_in,
                              void* d_out, int out_size, void* d_ws, size_t ws_size,
                              hipStream_t stream)
{
    const float* x     = (const float*)d_in[0];
    const float* w1    = (const float*)d_in[1];
    const float* b1    = (const float*)d_in[2];
    const float* sw    = (const float*)d_in[3];
    const float* sbias = (const float*)d_in[4];
    const float* lw    = (const float*)d_in[5];
    const float* lb    = (const float*)d_in[6];
    const int*   imh   = (const int*)d_in[7];
    const int*   imw   = (const int*)d_in[8];
    float* out = (float*)d_out;
    char* ws = (char*)d_ws;

    float* wtW     = (float*)(ws + 0);
    float* featW   = (float*)(ws + 9437184);
    float* boxesW  = (float*)(ws + 71696384);
    float* scoresW = (float*)(ws + 76073984);
    float* sbW     = (float*)(ws + 77168384);
    float* bbsW    = (float*)(ws + 77360384);
    float* areasW  = (float*)(ws + 78128384);
    u64*   maskW   = (u64*)(ws + 78320384);

    float* out0 = out;            // rpn_locs   (8,34200,4)
    float* out1 = out + 1094400;  // rpn_scores (8,34200,2)
    float* out2 = out + 1641600;  // rois       (2400,4)
    float* out3 = out + 1651200;  // anchors    (34200,4)

    hipLaunchKernelGGL(k_wt, dim3(16, 16, 9), dim3(32, 8), 0, stream, w1, wtW);
    hipLaunchKernelGGL(k_anch, dim3((NA + 255) / 256), dim3(256), 0, stream, out3);
    hipLaunchKernelGGL(k_conv, dim3(30, 4, NB), dim3(128), 0, stream, x, wtW, b1, featW);
    hipLaunchKernelGGL(k_heads, dim3(60, NB), dim3(256), 0, stream,
                       featW, lw, lb, sw, sbias, imh, imw, out0, out1, boxesW, scoresW);
    hipLaunchKernelGGL(k_select, dim3(NB), dim3(1024), NPAD * 8 + 256 * 4, stream,
                       scoresW, (const float4*)boxesW, sbW, (float4*)bbsW, areasW);
    hipLaunchKernelGGL(k_mask, dim3(94, 24, NB), dim3(256), 0, stream,
                       (const float4*)bbsW, areasW, maskW);
    hipLaunchKernelGGL(k_scan, dim3(NB), dim3(64), 0, stream,
                       sbW, (const float4*)bbsW, maskW, out2);
}

// Round 3
// 1384.312 us; speedup vs baseline: 4.7082x; 4.7082x over previous
//
#include <hip/hip_runtime.h>
#include <stdint.h>
#include <math.h>

typedef unsigned long long u64;
typedef unsigned int u32;
typedef _Float16 half8 __attribute__((ext_vector_type(8)));
typedef float f32x4 __attribute__((ext_vector_type(4)));

#define CC   512
#define HH   50
#define WW2  76
#define PP   3800      // HH*WW2
#define NB   8
#define NA   34200     // PP*9
#define PRE  6000
#define POST 300
#define MWORDS 96      // u64 words per mask row (94 used, padded)
#define NPAD 8192      // bitonic sort size

// ---------------- workspace layout (bytes) ----------------
// xh    @ 0            15,564,800   (4 img * 3800 * 512 * 2B)   [per-batch]
// xl    @ 15,564,800   15,564,800
// wh    @ 31,129,600    4,718,592   (512*9*512*2B)
// wl    @ 35,848,192    4,718,592
// feat  @ 40,566,784   62,259,200   (8*512*3800*4)
// boxes @ 102,825,984   4,377,600
// scores@ 107,203,584   1,094,400
// sb    @ 108,297,984     192,000
// bbs   @ 108,489,984     768,000
// areas @ 109,257,984     192,000
// mask  @ 0            36,864,000   [overlays xh/xl/wh — dead by k_mask time]
// total 109.4 MB (<= 115.7 MB proven safe in rounds 1-2)

__device__ __forceinline__ u32 skey(float f) {
    u32 u = __float_as_uint(f);
    return (u & 0x80000000u) ? ~u : (u | 0x80000000u);
}

__device__ __forceinline__ float4 anchor_at(int p, int a) {
    const float rv[3] = {0.5f, 1.0f, 2.0f};
    const float sv[3] = {8.0f, 16.0f, 32.0f};
    int ri = a / 3, si = a % 3;
    float s16 = 16.0f * sv[si];
    float hh = s16 * sqrtf(rv[ri]);
    float ww = s16 * sqrtf(1.0f / rv[ri]);
    float bx1 = 8.0f - 0.5f * ww, by1 = 8.0f - 0.5f * hh;
    float bx2 = 8.0f + 0.5f * ww, by2 = 8.0f + 0.5f * hh;
    float sx = (float)((p % WW2) * 16);
    float sy = (float)((p / WW2) * 16);
    return make_float4(sx + bx1, sy + by1, sx + bx2, sy + by2);
}

// ---------------- kernel: split x into f16 hi/lo, transposed [p][c] --------------
// grid (119, 16, 4), block (32,8)
__global__ void k_split_x(const float* __restrict__ x, _Float16* __restrict__ xh,
                          _Float16* __restrict__ xl) {
    __shared__ float S[32][33];
    int zim = blockIdx.z;
    int p0 = blockIdx.x * 32, c0 = blockIdx.y * 32;
    int tx = threadIdx.x, ty0 = threadIdx.y;
    const float* xi = x + (size_t)zim * CC * PP;
#pragma unroll
    for (int yy = 0; yy < 32; yy += 8) {
        int cty = c0 + ty0 + yy, ptx = p0 + tx;
        S[ty0 + yy][tx] = (ptx < PP) ? xi[(size_t)cty * PP + ptx] : 0.f;
    }
    __syncthreads();
#pragma unroll
    for (int yy = 0; yy < 32; yy += 8) {
        int p = p0 + ty0 + yy;
        if (p < PP) {
            float v = S[tx][ty0 + yy];
            _Float16 h = (_Float16)v;
            float r = v - (float)h;
            size_t o = (size_t)(zim * PP + p) * 512 + c0 + tx;
            xh[o] = h;
            xl[o] = (_Float16)(r * 2048.0f);
        }
    }
}

// ---------------- kernel: split conv1 weights into f16 hi/lo [co][idx][ci] -------
// grid 512, block 256
__global__ void k_split_w(const float* __restrict__ w, _Float16* __restrict__ wh,
                          _Float16* __restrict__ wl) {
    __shared__ float S[4608];
    int co = blockIdx.x;
    for (int t = threadIdx.x; t < 4608; t += 256) S[t] = w[(size_t)co * 4608 + t];
    __syncthreads();
    for (int e = threadIdx.x; e < 4608; e += 256) {
        int idx = e >> 9, cc = e & 511;
        float v = S[cc * 9 + idx];
        _Float16 h = (_Float16)v;
        float r = v - (float)h;
        wh[(size_t)co * 4608 + e] = h;
        wl[(size_t)co * 4608 + e] = (_Float16)(r * 2048.0f);
    }
}

// ---------------- kernel: anchors output ----------------
__global__ void k_anch(float* __restrict__ out3) {
    int t = blockIdx.x * 256 + threadIdx.x;
    if (t >= NA) return;
    int a = t % 9, p = t / 9;
    ((float4*)out3)[t] = anchor_at(p, a);
}

// ---------------- kernel: 3x3 conv via split-f16 MFMA implicit GEMM --------------
// grid (30, 4, 4), block 256 (4 waves, 2x2), BM=BN=128, BK=32.
// acc = hi*hi ; acc2 = hi*lo' + lo'*hi (lo' = lo*2^11); out = acc + acc2/2^11.
// LDS: 2 buffers x (A_hi|A_lo|B_hi|B_lo) frag-major (slot = lane*16B) = 64 KB dyn.
__global__ __launch_bounds__(256, 2) void k_conv(
    const _Float16* __restrict__ xh, const _Float16* __restrict__ xl,
    const _Float16* __restrict__ wh, const _Float16* __restrict__ wl,
    const float* __restrict__ bias, float* __restrict__ feat, int imgbase)
{
    extern __shared__ _Float16 lds[];
    const int tid = threadIdx.x;
    const int m0 = blockIdx.x * 128, n0 = blockIdx.y * 128;
    const int zim = blockIdx.z;
    const _Float16* xhi = xh + (size_t)zim * CC * PP;
    const _Float16* xlo = xl + (size_t)zim * CC * PP;

    const int mA0 = tid >> 2, jA0 = tid & 3;   // chunk 0: rows 0..63
    const int mA1 = 64 + (tid >> 2);           // chunk 1: rows 64..127

    f32x4 acc[4][4], acc2[4][4];
#pragma unroll
    for (int i = 0; i < 4; ++i)
#pragma unroll
        for (int j = 0; j < 4; ++j) {
            acc[i][j] = f32x4{0.f, 0.f, 0.f, 0.f};
            acc2[i][j] = f32x4{0.f, 0.f, 0.f, 0.f};
        }

    uint4 pa0h, pa0l, pa1h, pa1l, pb0h, pb0l, pb1h, pb1l;

    auto ld_a = [&](int m, int idx, int c0, uint4& vh, uint4& vl) {
        int dy = idx / 3 - 1, dx = idx % 3 - 1;
        int p = m0 + m;
        int px = p % 76, py = p / 76;
        bool av = (p < PP) && ((unsigned)(py + dy) < 50u) && ((unsigned)(px + dx) < 76u);
        if (av) {
            size_t off = (size_t)(p + dy * 76 + dx) * 512 + c0 + jA0 * 8;
            vh = *(const uint4*)(xhi + off);
            vl = *(const uint4*)(xlo + off);
        } else {
            vh = make_uint4(0, 0, 0, 0);
            vl = make_uint4(0, 0, 0, 0);
        }
    };
    auto ld_b = [&](int n, int idx, int c0, uint4& vh, uint4& vl) {
        size_t off = (size_t)((n0 + n) * 9 + idx) * 512 + c0 + jA0 * 8;
        vh = *(const uint4*)(wh + off);
        vl = *(const uint4*)(wl + off);
    };
    auto stage_load = [&](int kk) {
        int idx = kk >> 4, c0 = (kk & 15) << 5;
        ld_a(mA0, idx, c0, pa0h, pa0l);
        ld_a(mA1, idx, c0, pa1h, pa1l);
        ld_b(mA0, idx, c0, pb0h, pb0l);
        ld_b(mA1, idx, c0, pb1h, pb1l);
    };
    // frag-major slot: ((m>>4)*64 + (m&15) + j0*16)*8 halves
    const int sl0 = ((mA0 >> 4) * 64 + (mA0 & 15) + jA0 * 16) * 8;
    const int sl1 = ((mA1 >> 4) * 64 + (mA1 & 15) + jA0 * 16) * 8;
    auto stage_write = [&](int buf) {
        _Float16* L = lds + buf * 16384;
        *(uint4*)(L + sl0)         = pa0h;
        *(uint4*)(L + 4096 + sl0)  = pa0l;
        *(uint4*)(L + sl1)         = pa1h;
        *(uint4*)(L + 4096 + sl1)  = pa1l;
        *(uint4*)(L + 8192 + sl0)  = pb0h;
        *(uint4*)(L + 12288 + sl0) = pb0l;
        *(uint4*)(L + 8192 + sl1)  = pb1h;
        *(uint4*)(L + 12288 + sl1) = pb1l;
    };

    const int lane = tid & 63, wave = tid >> 6;
    const int wm = wave & 1, wn = wave >> 1;
    auto compute = [&](int buf) {
        const _Float16* L = lds + buf * 16384;
        half8 ah[4], al[4];
#pragma unroll
        for (int mi = 0; mi < 4; ++mi) {
            int slot = ((wm * 4 + mi) * 64 + lane) * 8;
            ah[mi] = *(const half8*)(L + slot);
            al[mi] = *(const half8*)(L + 4096 + slot);
        }
#pragma unroll
        for (int ni = 0; ni < 4; ++ni) {
            int slot = ((wn * 4 + ni) * 64 + lane) * 8;
            half8 bh = *(const half8*)(L + 8192 + slot);
            half8 bl = *(const half8*)(L + 12288 + slot);
#pragma unroll
            for (int mi = 0; mi < 4; ++mi) {
                acc[mi][ni]  = __builtin_amdgcn_mfma_f32_16x16x32_f16(ah[mi], bh, acc[mi][ni], 0, 0, 0);
                acc2[mi][ni] = __builtin_amdgcn_mfma_f32_16x16x32_f16(ah[mi], bl, acc2[mi][ni], 0, 0, 0);
                acc2[mi][ni] = __builtin_amdgcn_mfma_f32_16x16x32_f16(al[mi], bh, acc2[mi][ni], 0, 0, 0);
            }
        }
    };

    stage_load(0);
    stage_write(0);
    __syncthreads();
    for (int kk = 0; kk < 144; ++kk) {
        int buf = kk & 1;
        if (kk + 1 < 144) stage_load(kk + 1);
        compute(buf);
        if (kk + 1 < 144) stage_write(1 - buf);
        __syncthreads();
    }

    // epilogue: C/D 16x16 layout col=lane&15, row=(lane>>4)*4+reg
    float* fimg = feat + (size_t)(imgbase + zim) * CC * PP;
    const int q = lane >> 4, cl = lane & 15;
#pragma unroll
    for (int ni = 0; ni < 4; ++ni) {
        int n = n0 + (wn * 4 + ni) * 16 + cl;
        float bs = bias[n];
#pragma unroll
        for (int mi = 0; mi < 4; ++mi) {
            int mb = m0 + (wm * 4 + mi) * 16 + q * 4;
            if (mb < PP) {
                float4 v;
                v.x = fmaxf(acc[mi][ni][0] + acc2[mi][ni][0] * (1.f / 2048.f) + bs, 0.f);
                v.y = fmaxf(acc[mi][ni][1] + acc2[mi][ni][1] * (1.f / 2048.f) + bs, 0.f);
                v.z = fmaxf(acc[mi][ni][2] + acc2[mi][ni][2] * (1.f / 2048.f) + bs, 0.f);
                v.w = fmaxf(acc[mi][ni][3] + acc2[mi][ni][3] * (1.f / 2048.f) + bs, 0.f);
                *(float4*)&fimg[(size_t)n * PP + mb] = v;
            }
        }
    }
}

// ---------------- kernel: fused 1x1 heads + softmax + bbox decode ----------------
// grid (60, 8), block 256. Each block: 64 spatial positions.
__global__ __launch_bounds__(256) void k_heads(
    const float* __restrict__ feat,
    const float* __restrict__ lw, const float* __restrict__ lb,
    const float* __restrict__ sw, const float* __restrict__ sbias,
    const int* __restrict__ imh_p, const int* __restrict__ imw_p,
    float* __restrict__ out0, float* __restrict__ out1,
    float* __restrict__ boxes, float* __restrict__ scores)
{
    int img = blockIdx.y;
    int p0 = blockIdx.x * 64;
    int tid = threadIdx.x;
    int pl = tid & 63, cg = tid >> 6;
    __shared__ float Fs[32][65];
    __shared__ float Wsh[54][32];
    __shared__ float O[54][64];
    float acc[14];
#pragma unroll
    for (int j = 0; j < 14; ++j) acc[j] = 0.f;
    const float* fimg = feat + (size_t)img * CC * PP;

    for (int c0 = 0; c0 < CC; c0 += 32) {
        __syncthreads();
#pragma unroll
        for (int i = 0; i < 8; ++i) {
            int k = cg * 8 + i;
            int p = p0 + pl;
            Fs[k][pl] = (p < PP) ? fimg[(size_t)(c0 + k) * PP + p] : 0.f;
        }
        for (int e = tid; e < 54 * 32; e += 256) {
            int c = e >> 5, k = e & 31;
            Wsh[c][k] = (c < 36) ? lw[c * CC + c0 + k] : sw[(c - 36) * CC + c0 + k];
        }
        __syncthreads();
#pragma unroll
        for (int k = 0; k < 32; ++k) {
            float f = Fs[k][pl];
#pragma unroll
            for (int j = 0; j < 14; ++j) {
                int c = cg * 14 + j;
                if (c < 54) acc[j] = fmaf(Wsh[c][k], f, acc[j]);
            }
        }
    }
    __syncthreads();
#pragma unroll
    for (int j = 0; j < 14; ++j) {
        int c = cg * 14 + j;
        if (c < 54) O[c][pl] = acc[j] + (c < 36 ? lb[c] : sbias[c - 36]);
    }
    __syncthreads();

    float fimh = (float)(*imh_p), fimw = (float)(*imw_p);
    for (int e = tid; e < 576; e += 256) {
        int pl2 = e / 9, a = e % 9;
        int p = p0 + pl2;
        if (p >= PP) continue;
        float l0 = O[a * 4 + 0][pl2], l1 = O[a * 4 + 1][pl2];
        float l2v = O[a * 4 + 2][pl2], l3 = O[a * 4 + 3][pl2];
        float s0 = O[36 + a * 2][pl2], s1 = O[36 + a * 2 + 1][pl2];
        size_t ai = (size_t)img * NA + (size_t)p * 9 + a;
        *(float4*)&out0[ai * 4] = make_float4(l0, l1, l2v, l3);
        *(float2*)&out1[ai * 2] = make_float2(s0, s1);
        float mx = fmaxf(s0, s1);
        float e0 = expf(s0 - mx), e1 = expf(s1 - mx);
        float fg = e1 / (e0 + e1);
        float4 an = anchor_at(p, a);
        float aw = an.z - an.x, ah = an.w - an.y;
        float ax = an.x + 0.5f * aw, ay = an.y + 0.5f * ah;
        float cx = l0 * aw + ax;
        float cy = l1 * ah + ay;
        float wb = expf(l2v) * aw, hb = expf(l3) * ah;
        float x1 = cx - 0.5f * wb, y1 = cy - 0.5f * hb;
        float x2 = cx + 0.5f * wb, y2 = cy + 0.5f * hb;
        x1 = fminf(fmaxf(x1, 0.f), fimw);
        x2 = fminf(fmaxf(x2, 0.f), fimw);
        y1 = fminf(fmaxf(y1, 0.f), fimh);
        y2 = fminf(fmaxf(y2, 0.f), fimh);
        bool valid = ((x2 - x1) >= 16.0f) && ((y2 - y1) >= 16.0f);
        ((float4*)boxes)[ai] = make_float4(x1, y1, x2, y2);
        scores[ai] = valid ? fg : -INFINITY;
    }
}

// ---------------- kernel: per-image top-6000 select + stable sort (LDS) ----------
__global__ __launch_bounds__(1024) void k_select(
    const float* __restrict__ scores, const float4* __restrict__ boxes,
    float* __restrict__ sb, float4* __restrict__ bbs, float* __restrict__ areas)
{
    extern __shared__ u64 dyn[];
    u64* arr = dyn;
    u32* hist = (u32*)(dyn + NPAD);
    __shared__ u32 s_pref, s_rem, s_cnt;
    int img = blockIdx.x;
    int tid = threadIdx.x;
    const float* sc = scores + (size_t)img * NA;
    if (tid == 0) { s_pref = 0; s_rem = PRE; }
    u32 pmask = 0;
    for (int sh = 24; sh >= 0; sh -= 8) {
        for (int i = tid; i < 256; i += 1024) hist[i] = 0;
        __syncthreads();
        u32 pref = s_pref;
        for (int e = tid; e < NA; e += 1024) {
            u32 k = skey(sc[e]);
            if ((k & pmask) == pref) atomicAdd(&hist[(k >> sh) & 255], 1);
        }
        __syncthreads();
        if (tid == 0) {
            u32 c = 0; u32 rem = s_rem; u32 pv = s_pref;
            for (int d = 255; d >= 0; --d) {
                u32 h = hist[d];
                if (c + h >= rem) { s_pref = pv | ((u32)d << sh); s_rem = rem - c; break; }
                c += h;
            }
        }
        __syncthreads();
        pmask |= (0xFFu << sh);
    }
    u32 T = s_pref;
    if (tid == 0) s_cnt = 0;
    __syncthreads();
    for (int e = tid; e < NA; e += 1024) {
        u32 k = skey(sc[e]);
        if (k >= T) {
            u32 pos = atomicAdd(&s_cnt, 1);
            if (pos < NPAD) arr[pos] = ((u64)k << 32) | (u64)(~(u32)e);
        }
    }
    __syncthreads();
    u32 n = s_cnt; if (n > NPAD) n = NPAD;
    for (u32 t2 = n + tid; t2 < NPAD; t2 += 1024) arr[t2] = 0;
    for (u32 size = 2; size <= NPAD; size <<= 1) {
        for (u32 stride = size >> 1; stride > 0; stride >>= 1) {
            __syncthreads();
            for (u32 t2 = tid; t2 < NPAD / 2; t2 += 1024) {
                u32 i = 2 * t2 - (t2 & (stride - 1));
                u32 j = i + stride;
                u64 a = arr[i], b = arr[j];
                bool desc = ((i & size) == 0);
                if (desc ? (a < b) : (a > b)) { arr[i] = b; arr[j] = a; }
            }
        }
    }
    __syncthreads();
    for (int t2 = tid; t2 < PRE; t2 += 1024) {
        u64 v = arr[t2];
        u32 e = ~(u32)v;
        float s = sc[e];
        float4 bx = boxes[(size_t)img * NA + e];
        sb[img * PRE + t2] = s;
        bbs[img * PRE + t2] = bx;
        areas[img * PRE + t2] = (bx.z - bx.x) * (bx.w - bx.y);
    }
}

// ---------------- kernel: IoU suppression bitmask ----------------
__global__ __launch_bounds__(256) void k_mask(
    const float4* __restrict__ bbs, const float* __restrict__ areas,
    u64* __restrict__ mask)
{
    int img = blockIdx.z, iT = blockIdx.x, jT = blockIdx.y;
    int tid = threadIdx.x;
    __shared__ float4 jb[256];
    __shared__ float ja[256];
    int jj = jT * 256 + tid;
    jb[tid] = (jj < PRE) ? bbs[(size_t)img * PRE + jj] : make_float4(0, 0, 0, 0);
    ja[tid] = (jj < PRE) ? areas[img * PRE + jj] : 0.f;
    __syncthreads();
    int i = iT * 64 + (tid & 63);
    int jw = jT * 4 + (tid >> 6);
    if (i >= PRE) return;
    float4 bi = bbs[(size_t)img * PRE + i];
    float ai = areas[img * PRE + i];
    int j0 = (tid >> 6) * 64;
    u64 m = 0;
#pragma unroll 4
    for (int b = 0; b < 64; ++b) {
        int j = jw * 64 + b;
        if (j >= PRE) break;
        if (j > i) {
            float4 bj = jb[j0 + b];
            float xx1 = fmaxf(bi.x, bj.x), yy1 = fmaxf(bi.y, bj.y);
            float xx2 = fminf(bi.z, bj.z), yy2 = fminf(bi.w, bj.w);
            float iw = fmaxf(xx2 - xx1, 0.f), ih2 = fmaxf(yy2 - yy1, 0.f);
            float inter = iw * ih2;
            float iou = inter / (ai + ja[j0 + b] - inter + 1e-9f);
            if (iou > 0.7f) m |= (1ull << b);
        }
    }
    mask[((size_t)img * PRE + i) * MWORDS + jw] = m;
}

// ---------------- kernel: sequential NMS scan (early-exit at 300 keeps) ----------
__global__ __launch_bounds__(64) void k_scan(
    const float* __restrict__ sb, const float4* __restrict__ bbs,
    const u64* __restrict__ mask, float* __restrict__ out2)
{
    int img = blockIdx.x;
    int lane = threadIdx.x;
    __shared__ u64 keep[96];
    __shared__ int list[POST];
    for (int w = lane; w < 96; w += 64) {
        u64 bits = 0;
        if (w < 94) {
            for (int b = 0; b < 64; ++b) {
                int j = w * 64 + b;
                if (j < PRE && isfinite(sb[img * PRE + j])) bits |= (1ull << b);
            }
        }
        keep[w] = bits;
    }
    __syncthreads();
    int n = 0;
    for (int w = 0; w < 94 && n < POST; ++w) {
        u64 cur = keep[w];
        while (cur) {
            int b = __builtin_ctzll(cur);
            int i = w * 64 + b;
            if (lane == 0) list[n] = i;
            n++;
            if (n >= POST) break;
            const u64* mrow = mask + ((size_t)img * PRE + i) * MWORDS;
            if (lane < 47) {
                ulonglong2 mv = *(const ulonglong2*)&mrow[2 * lane];
                keep[2 * lane]     &= ~mv.x;
                keep[2 * lane + 1] &= ~mv.y;
            }
            __syncthreads();
            u64 kw = keep[w];
            cur = (b >= 63) ? 0ull : ((kw >> (b + 1)) << (b + 1));
            __syncthreads();
        }
    }
    __syncthreads();
    for (int e = lane; e < POST; e += 64) {
        float4 bx = (e < n) ? bbs[(size_t)img * PRE + list[e]] : make_float4(0, 0, 0, 0);
        *(float4*)&out2[((size_t)img * POST + e) * 4] = bx;
    }
}

extern "C" void kernel_launch(void* const* d_in, const int* in_sizes, int n_in,
                              void* d_out, int out_size, void* d_ws, size_t ws_size,
                              hipStream_t stream)
{
    const float* x     = (const float*)d_in[0];
    const float* w1    = (const float*)d_in[1];
    const float* b1    = (const float*)d_in[2];
    const float* sw    = (const float*)d_in[3];
    const float* sbias = (const float*)d_in[4];
    const float* lw    = (const float*)d_in[5];
    const float* lb    = (const float*)d_in[6];
    const int*   imh   = (const int*)d_in[7];
    const int*   imw   = (const int*)d_in[8];
    float* out = (float*)d_out;
    char* ws = (char*)d_ws;

    _Float16* xhW   = (_Float16*)(ws + 0);
    _Float16* xlW   = (_Float16*)(ws + 15564800);
    _Float16* whW   = (_Float16*)(ws + 31129600);
    _Float16* wlW   = (_Float16*)(ws + 35848192);
    float*    featW = (float*)(ws + 40566784);
    float*    boxesW  = (float*)(ws + 102825984);
    float*    scoresW = (float*)(ws + 107203584);
    float*    sbW     = (float*)(ws + 108297984);
    float*    bbsW    = (float*)(ws + 108489984);
    float*    areasW  = (float*)(ws + 109257984);
    u64*      maskW   = (u64*)(ws + 0);   // overlays dead split buffers

    float* out0 = out;            // rpn_locs   (8,34200,4)
    float* out1 = out + 1094400;  // rpn_scores (8,34200,2)
    float* out2 = out + 1641600;  // rois       (2400,4)
    float* out3 = out + 1651200;  // anchors    (34200,4)

    hipLaunchKernelGGL(k_split_w, dim3(512), dim3(256), 0, stream, w1, whW, wlW);
    hipLaunchKernelGGL(k_anch, dim3((NA + 255) / 256), dim3(256), 0, stream, out3);
    for (int b = 0; b < 2; ++b) {
        hipLaunchKernelGGL(k_split_x, dim3(119, 16, 4), dim3(32, 8), 0, stream,
                           x + (size_t)b * 4 * CC * PP, xhW, xlW);
        hipLaunchKernelGGL(k_conv, dim3(30, 4, 4), dim3(256), 65536, stream,
                           xhW, xlW, whW, wlW, b1, featW, b * 4);
    }
    hipLaunchKernelGGL(k_heads, dim3(60, NB), dim3(256), 0, stream,
                       featW, lw, lb, sw, sbias, imh, imw, out0, out1, boxesW, scoresW);
    hipLaunchKernelGGL(k_select, dim3(NB), dim3(1024), NPAD * 8 + 256 * 4, stream,
                       scoresW, (const float4*)boxesW, sbW, (float4*)bbsW, areasW);
    hipLaunchKernelGGL(k_mask, dim3(94, 24, NB), dim3(256), 0, stream,
                       (const float4*)bbsW, areasW, maskW);
    hipLaunchKernelGGL(k_scan, dim3(NB), dim3(64), 0, stream,
                       sbW, (const float4*)bbsW, maskW, out2);
}

// Round 4
// 1146.907 us; speedup vs baseline: 5.6828x; 1.2070x over previous
//
#include <hip/hip_runtime.h>
#include <stdint.h>
#include <math.h>

typedef unsigned long long u64;
typedef unsigned int u32;
typedef _Float16 half8 __attribute__((ext_vector_type(8)));
typedef float f32x4 __attribute__((ext_vector_type(4)));

#define CC   512
#define HH   50
#define WW2  76
#define PP   3800      // HH*WW2
#define NB   8
#define NA   34200     // PP*9
#define PRE  6000
#define POST 300
#define MWORDS 96      // u64 words per mask row (94 used, padded)
#define NPAD 8192      // bitonic sort size

// ---------------- workspace layout (bytes) ----------------
// wh2   @ 0            65,536      (64 x 512 f16)  [head weights hi]
// wl2   @ 65,536       65,536
// wh    @ 131,072      4,718,592   (512*9*512 f16) [conv weights hi]
// wl    @ 4,849,664    4,718,592
// xh    @ 9,568,256    15,564,800  (4 img * 3800 * 512 f16, per-batch)
// xl    @ 25,133,056   15,564,800
// --- after conv, xh/xl dead; overlay: ---
// O     @ 9,568,256    7,782,400   (8*3800*64 f32 head outputs)
// boxes @ 17,350,656   4,377,600
// scores@ 21,728,256   1,094,400
// sb    @ 22,822,656     192,000
// bbs   @ 23,014,656     768,000
// areas @ 23,782,656     192,000
// fh    @ 40,697,856   31,129,600  (8*3800*512 f16 feat hi, [p][c])
// fl    @ 71,827,456   31,129,600
// --- after k_hgemm, fh/fl dead; overlay: ---
// mask  @ 40,697,856   36,864,000
// peak 102,957,056 B (~103 MB, <= 115.7 MB proven safe)

__device__ __forceinline__ u32 skey(float f) {
    u32 u = __float_as_uint(f);
    return (u & 0x80000000u) ? ~u : (u | 0x80000000u);
}

__device__ __forceinline__ float4 anchor_at(int p, int a) {
    const float rv[3] = {0.5f, 1.0f, 2.0f};
    const float sv[3] = {8.0f, 16.0f, 32.0f};
    int ri = a / 3, si = a % 3;
    float s16 = 16.0f * sv[si];
    float hh = s16 * sqrtf(rv[ri]);
    float ww = s16 * sqrtf(1.0f / rv[ri]);
    float bx1 = 8.0f - 0.5f * ww, by1 = 8.0f - 0.5f * hh;
    float bx2 = 8.0f + 0.5f * ww, by2 = 8.0f + 0.5f * hh;
    float sx = (float)((p % WW2) * 16);
    float sy = (float)((p / WW2) * 16);
    return make_float4(sx + bx1, sy + by1, sx + bx2, sy + by2);
}

// ---------------- kernel: split x into f16 hi/lo, transposed [p][c] --------------
// grid (119, 16, 4), block (32,8)
__global__ void k_split_x(const float* __restrict__ x, _Float16* __restrict__ xh,
                          _Float16* __restrict__ xl) {
    __shared__ float S[32][33];
    int zim = blockIdx.z;
    int p0 = blockIdx.x * 32, c0 = blockIdx.y * 32;
    int tx = threadIdx.x, ty0 = threadIdx.y;
    const float* xi = x + (size_t)zim * CC * PP;
#pragma unroll
    for (int yy = 0; yy < 32; yy += 8) {
        int cty = c0 + ty0 + yy, ptx = p0 + tx;
        S[ty0 + yy][tx] = (ptx < PP) ? xi[(size_t)cty * PP + ptx] : 0.f;
    }
    __syncthreads();
#pragma unroll
    for (int yy = 0; yy < 32; yy += 8) {
        int p = p0 + ty0 + yy;
        if (p < PP) {
            float v = S[tx][ty0 + yy];
            _Float16 h = (_Float16)v;
            float r = v - (float)h;
            size_t o = (size_t)(zim * PP + p) * 512 + c0 + tx;
            xh[o] = h;
            xl[o] = (_Float16)(r * 2048.0f);
        }
    }
}

// ---------------- kernel: split conv1 weights into f16 hi/lo [co][idx][ci] -------
// grid 512, block 256
__global__ void k_split_w(const float* __restrict__ w, _Float16* __restrict__ wh,
                          _Float16* __restrict__ wl) {
    __shared__ float S[4608];
    int co = blockIdx.x;
    for (int t = threadIdx.x; t < 4608; t += 256) S[t] = w[(size_t)co * 4608 + t];
    __syncthreads();
    for (int e = threadIdx.x; e < 4608; e += 256) {
        int idx = e >> 9, cc = e & 511;
        float v = S[cc * 9 + idx];
        _Float16 h = (_Float16)v;
        float r = v - (float)h;
        wh[(size_t)co * 4608 + e] = h;
        wl[(size_t)co * 4608 + e] = (_Float16)(r * 2048.0f);
    }
}

// ---------------- kernel: split head weights into [64][512] f16 hi/lo -----------
// rows 0..35 = loc, 36..53 = score, 54..63 = zero. grid 64, block 512.
__global__ void k_split_w2(const float* __restrict__ lw, const float* __restrict__ sw,
                           _Float16* __restrict__ wh2, _Float16* __restrict__ wl2) {
    int row = blockIdx.x, k = threadIdx.x;
    float v = (row < 36) ? lw[row * 512 + k] : (row < 54 ? sw[(row - 36) * 512 + k] : 0.f);
    _Float16 h = (_Float16)v;
    float r = v - (float)h;
    wh2[row * 512 + k] = h;
    wl2[row * 512 + k] = (_Float16)(r * 2048.0f);
}

// ---------------- kernel: anchors output ----------------
__global__ void k_anch(float* __restrict__ out3) {
    int t = blockIdx.x * 256 + threadIdx.x;
    if (t >= NA) return;
    int a = t % 9, p = t / 9;
    ((float4*)out3)[t] = anchor_at(p, a);
}

// ---------------- kernel: 3x3 conv via split-f16 MFMA implicit GEMM --------------
// grid (30, 4, 4), block 256 (4 waves, 2x2), BM=BN=128, BK=32.
// Epilogue writes split-f16 feat fh/fl in [p][c] row-major.
__global__ __launch_bounds__(256, 2) void k_conv(
    const _Float16* __restrict__ xh, const _Float16* __restrict__ xl,
    const _Float16* __restrict__ wh, const _Float16* __restrict__ wl,
    const float* __restrict__ bias, _Float16* __restrict__ fh,
    _Float16* __restrict__ fl, int imgbase)
{
    extern __shared__ _Float16 lds[];
    const int tid = threadIdx.x;
    const int m0 = blockIdx.x * 128, n0 = blockIdx.y * 128;
    const int zim = blockIdx.z;
    const _Float16* xhi = xh + (size_t)zim * CC * PP;
    const _Float16* xlo = xl + (size_t)zim * CC * PP;

    const int mA0 = tid >> 2, jA0 = tid & 3;
    const int mA1 = 64 + (tid >> 2);

    f32x4 acc[4][4], acc2[4][4];
#pragma unroll
    for (int i = 0; i < 4; ++i)
#pragma unroll
        for (int j = 0; j < 4; ++j) {
            acc[i][j] = f32x4{0.f, 0.f, 0.f, 0.f};
            acc2[i][j] = f32x4{0.f, 0.f, 0.f, 0.f};
        }

    uint4 pa0h, pa0l, pa1h, pa1l, pb0h, pb0l, pb1h, pb1l;

    auto ld_a = [&](int m, int idx, int c0, uint4& vh, uint4& vl) {
        int dy = idx / 3 - 1, dx = idx % 3 - 1;
        int p = m0 + m;
        int px = p % 76, py = p / 76;
        bool av = (p < PP) && ((unsigned)(py + dy) < 50u) && ((unsigned)(px + dx) < 76u);
        if (av) {
            size_t off = (size_t)(p + dy * 76 + dx) * 512 + c0 + jA0 * 8;
            vh = *(const uint4*)(xhi + off);
            vl = *(const uint4*)(xlo + off);
        } else {
            vh = make_uint4(0, 0, 0, 0);
            vl = make_uint4(0, 0, 0, 0);
        }
    };
    auto ld_b = [&](int n, int idx, int c0, uint4& vh, uint4& vl) {
        size_t off = (size_t)((n0 + n) * 9 + idx) * 512 + c0 + jA0 * 8;
        vh = *(const uint4*)(wh + off);
        vl = *(const uint4*)(wl + off);
    };
    auto stage_load = [&](int kk) {
        int idx = kk >> 4, c0 = (kk & 15) << 5;
        ld_a(mA0, idx, c0, pa0h, pa0l);
        ld_a(mA1, idx, c0, pa1h, pa1l);
        ld_b(mA0, idx, c0, pb0h, pb0l);
        ld_b(mA1, idx, c0, pb1h, pb1l);
    };
    const int sl0 = ((mA0 >> 4) * 64 + (mA0 & 15) + jA0 * 16) * 8;
    const int sl1 = ((mA1 >> 4) * 64 + (mA1 & 15) + jA0 * 16) * 8;
    auto stage_write = [&](int buf) {
        _Float16* L = lds + buf * 16384;
        *(uint4*)(L + sl0)         = pa0h;
        *(uint4*)(L + 4096 + sl0)  = pa0l;
        *(uint4*)(L + sl1)         = pa1h;
        *(uint4*)(L + 4096 + sl1)  = pa1l;
        *(uint4*)(L + 8192 + sl0)  = pb0h;
        *(uint4*)(L + 12288 + sl0) = pb0l;
        *(uint4*)(L + 8192 + sl1)  = pb1h;
        *(uint4*)(L + 12288 + sl1) = pb1l;
    };

    const int lane = tid & 63, wave = tid >> 6;
    const int wm = wave & 1, wn = wave >> 1;
    auto compute = [&](int buf) {
        const _Float16* L = lds + buf * 16384;
        half8 ah[4], al[4];
#pragma unroll
        for (int mi = 0; mi < 4; ++mi) {
            int slot = ((wm * 4 + mi) * 64 + lane) * 8;
            ah[mi] = *(const half8*)(L + slot);
            al[mi] = *(const half8*)(L + 4096 + slot);
        }
#pragma unroll
        for (int ni = 0; ni < 4; ++ni) {
            int slot = ((wn * 4 + ni) * 64 + lane) * 8;
            half8 bh = *(const half8*)(L + 8192 + slot);
            half8 bl = *(const half8*)(L + 12288 + slot);
#pragma unroll
            for (int mi = 0; mi < 4; ++mi) {
                acc[mi][ni]  = __builtin_amdgcn_mfma_f32_16x16x32_f16(ah[mi], bh, acc[mi][ni], 0, 0, 0);
                acc2[mi][ni] = __builtin_amdgcn_mfma_f32_16x16x32_f16(ah[mi], bl, acc2[mi][ni], 0, 0, 0);
                acc2[mi][ni] = __builtin_amdgcn_mfma_f32_16x16x32_f16(al[mi], bh, acc2[mi][ni], 0, 0, 0);
            }
        }
    };

    stage_load(0);
    stage_write(0);
    __syncthreads();
    for (int kk = 0; kk < 144; ++kk) {
        int buf = kk & 1;
        if (kk + 1 < 144) stage_load(kk + 1);
        compute(buf);
        if (kk + 1 < 144) stage_write(1 - buf);
        __syncthreads();
    }

    // epilogue: C/D 16x16 layout col=lane&15 (n), row=(lane>>4)*4+reg (m).
    // bias+relu then split-f16 write to fh/fl [row][c].
    const int q = lane >> 4, cl = lane & 15;
    const size_t rowbase = (size_t)(imgbase + zim) * PP;
#pragma unroll
    for (int ni = 0; ni < 4; ++ni) {
        int n = n0 + (wn * 4 + ni) * 16 + cl;
        float bs = bias[n];
#pragma unroll
        for (int mi = 0; mi < 4; ++mi) {
            int mb = m0 + (wm * 4 + mi) * 16 + q * 4;
            if (mb < PP) {
#pragma unroll
                for (int r = 0; r < 4; ++r) {
                    float v = fmaxf(acc[mi][ni][r] + acc2[mi][ni][r] * (1.f / 2048.f) + bs, 0.f);
                    _Float16 h = (_Float16)v;
                    float rr = v - (float)h;
                    size_t o = (rowbase + mb + r) * 512 + n;
                    fh[o] = h;
                    fl[o] = (_Float16)(rr * 2048.0f);
                }
            }
        }
    }
}

// ---------------- kernel: head GEMM via split-f16 MFMA ---------------------------
// O[img][p][64] = feat[p][512] x W2^T.  grid (60, 8), block 256 (4 waves).
// m-tile 64: wave w -> rows p0+w*16..+15; n = 64 (4 frags); K=512. No LDS.
__global__ __launch_bounds__(256) void k_hgemm(
    const _Float16* __restrict__ fh, const _Float16* __restrict__ fl,
    const _Float16* __restrict__ wh2, const _Float16* __restrict__ wl2,
    const float* __restrict__ lb, const float* __restrict__ sbias,
    float* __restrict__ O)
{
    const int img = blockIdx.y;
    const int p0 = blockIdx.x * 64;
    const int wave = threadIdx.x >> 6, lane = threadIdx.x & 63;
    const int q8 = (lane >> 4) * 8;
    int arow = img * PP + p0 + wave * 16 + (lane & 15);
    if (arow >= NB * PP) arow = NB * PP - 1;   // clamp tail reads
    const _Float16* fhp = fh + (size_t)arow * 512 + q8;
    const _Float16* flp = fl + (size_t)arow * 512 + q8;
    const _Float16* bhp = wh2 + (size_t)(lane & 15) * 512 + q8;
    const _Float16* blp = wl2 + (size_t)(lane & 15) * 512 + q8;

    f32x4 acc[4], acc2[4];
#pragma unroll
    for (int j = 0; j < 4; ++j) {
        acc[j] = f32x4{0.f, 0.f, 0.f, 0.f};
        acc2[j] = f32x4{0.f, 0.f, 0.f, 0.f};
    }

#pragma unroll 4
    for (int k0 = 0; k0 < 512; k0 += 32) {
        half8 ah = *(const half8*)(fhp + k0);
        half8 al = *(const half8*)(flp + k0);
#pragma unroll
        for (int nf = 0; nf < 4; ++nf) {
            half8 bh = *(const half8*)(bhp + (size_t)nf * 16 * 512 + k0);
            half8 bl = *(const half8*)(blp + (size_t)nf * 16 * 512 + k0);
            acc[nf]  = __builtin_amdgcn_mfma_f32_16x16x32_f16(ah, bh, acc[nf], 0, 0, 0);
            acc2[nf] = __builtin_amdgcn_mfma_f32_16x16x32_f16(ah, bl, acc2[nf], 0, 0, 0);
            acc2[nf] = __builtin_amdgcn_mfma_f32_16x16x32_f16(al, bh, acc2[nf], 0, 0, 0);
        }
    }

    // D: col = lane&15 (n within frag), row = (lane>>4)*4+reg (m within wave tile)
    const int q = lane >> 4, cl = lane & 15;
#pragma unroll
    for (int nf = 0; nf < 4; ++nf) {
        int n = nf * 16 + cl;
        float bs = (n < 36) ? lb[n] : (n < 54 ? sbias[n - 36] : 0.f);
#pragma unroll
        for (int r = 0; r < 4; ++r) {
            int m = p0 + wave * 16 + q * 4 + r;
            if (m < PP)
                O[((size_t)img * PP + m) * 64 + n] =
                    acc[nf][r] + acc2[nf][r] * (1.f / 2048.f) + bs;
        }
    }
}

// ---------------- kernel: decode heads -> outputs + boxes/scores -----------------
// one thread per (img, p, a). grid 1069, block 256.
__global__ __launch_bounds__(256) void k_post(
    const float* __restrict__ O,
    const int* __restrict__ imh_p, const int* __restrict__ imw_p,
    float* __restrict__ out0, float* __restrict__ out1,
    float* __restrict__ boxes, float* __restrict__ scores)
{
    int t = blockIdx.x * 256 + threadIdx.x;
    if (t >= NB * NA) return;
    int img = t / NA, r = t % NA;
    int p = r / 9, a = r % 9;
    const float* Op = O + ((size_t)img * PP + p) * 64;
    float4 loc = *(const float4*)(Op + a * 4);
    float2 sc = *(const float2*)(Op + 36 + a * 2);
    size_t ai = (size_t)img * NA + r;
    *(float4*)&out0[ai * 4] = loc;
    *(float2*)&out1[ai * 2] = sc;
    float mx = fmaxf(sc.x, sc.y);
    float e0 = expf(sc.x - mx), e1 = expf(sc.y - mx);
    float fg = e1 / (e0 + e1);
    float fimh = (float)(*imh_p), fimw = (float)(*imw_p);
    float4 an = anchor_at(p, a);
    float aw = an.z - an.x, ah = an.w - an.y;
    float ax = an.x + 0.5f * aw, ay = an.y + 0.5f * ah;
    float cx = loc.x * aw + ax;
    float cy = loc.y * ah + ay;
    float wb = expf(loc.z) * aw, hb = expf(loc.w) * ah;
    float x1 = cx - 0.5f * wb, y1 = cy - 0.5f * hb;
    float x2 = cx + 0.5f * wb, y2 = cy + 0.5f * hb;
    x1 = fminf(fmaxf(x1, 0.f), fimw);
    x2 = fminf(fmaxf(x2, 0.f), fimw);
    y1 = fminf(fmaxf(y1, 0.f), fimh);
    y2 = fminf(fmaxf(y2, 0.f), fimh);
    bool valid = ((x2 - x1) >= 16.0f) && ((y2 - y1) >= 16.0f);
    ((float4*)boxes)[ai] = make_float4(x1, y1, x2, y2);
    scores[ai] = valid ? fg : -INFINITY;
}

// ---------------- kernel: per-image top-6000 select + stable sort (LDS) ----------
__global__ __launch_bounds__(1024) void k_select(
    const float* __restrict__ scores, const float4* __restrict__ boxes,
    float* __restrict__ sb, float4* __restrict__ bbs, float* __restrict__ areas)
{
    extern __shared__ u64 dyn[];
    u64* arr = dyn;
    u32* hist = (u32*)(dyn + NPAD);
    __shared__ u32 s_pref, s_rem, s_cnt;
    int img = blockIdx.x;
    int tid = threadIdx.x;
    const float* sc = scores + (size_t)img * NA;
    if (tid == 0) { s_pref = 0; s_rem = PRE; }
    u32 pmask = 0;
    for (int sh = 24; sh >= 0; sh -= 8) {
        for (int i = tid; i < 256; i += 1024) hist[i] = 0;
        __syncthreads();
        u32 pref = s_pref;
        for (int e = tid; e < NA; e += 1024) {
            u32 k = skey(sc[e]);
            if ((k & pmask) == pref) atomicAdd(&hist[(k >> sh) & 255], 1);
        }
        __syncthreads();
        if (tid == 0) {
            u32 c = 0; u32 rem = s_rem; u32 pv = s_pref;
            for (int d = 255; d >= 0; --d) {
                u32 h = hist[d];
                if (c + h >= rem) { s_pref = pv | ((u32)d << sh); s_rem = rem - c; break; }
                c += h;
            }
        }
        __syncthreads();
        pmask |= (0xFFu << sh);
    }
    u32 T = s_pref;
    if (tid == 0) s_cnt = 0;
    __syncthreads();
    for (int e = tid; e < NA; e += 1024) {
        u32 k = skey(sc[e]);
        if (k >= T) {
            u32 pos = atomicAdd(&s_cnt, 1);
            if (pos < NPAD) arr[pos] = ((u64)k << 32) | (u64)(~(u32)e);
        }
    }
    __syncthreads();
    u32 n = s_cnt; if (n > NPAD) n = NPAD;
    for (u32 t2 = n + tid; t2 < NPAD; t2 += 1024) arr[t2] = 0;
    for (u32 size = 2; size <= NPAD; size <<= 1) {
        for (u32 stride = size >> 1; stride > 0; stride >>= 1) {
            __syncthreads();
            for (u32 t2 = tid; t2 < NPAD / 2; t2 += 1024) {
                u32 i = 2 * t2 - (t2 & (stride - 1));
                u32 j = i + stride;
                u64 a = arr[i], b = arr[j];
                bool desc = ((i & size) == 0);
                if (desc ? (a < b) : (a > b)) { arr[i] = b; arr[j] = a; }
            }
        }
    }
    __syncthreads();
    for (int t2 = tid; t2 < PRE; t2 += 1024) {
        u64 v = arr[t2];
        u32 e = ~(u32)v;
        float s = sc[e];
        float4 bx = boxes[(size_t)img * NA + e];
        sb[img * PRE + t2] = s;
        bbs[img * PRE + t2] = bx;
        areas[img * PRE + t2] = (bx.z - bx.x) * (bx.w - bx.y);
    }
}

// ---------------- kernel: IoU suppression bitmask ----------------
__global__ __launch_bounds__(256) void k_mask(
    const float4* __restrict__ bbs, const float* __restrict__ areas,
    u64* __restrict__ mask)
{
    int img = blockIdx.z, iT = blockIdx.x, jT = blockIdx.y;
    int tid = threadIdx.x;
    __shared__ float4 jb[256];
    __shared__ float ja[256];
    int jj = jT * 256 + tid;
    jb[tid] = (jj < PRE) ? bbs[(size_t)img * PRE + jj] : make_float4(0, 0, 0, 0);
    ja[tid] = (jj < PRE) ? areas[img * PRE + jj] : 0.f;
    __syncthreads();
    int i = iT * 64 + (tid & 63);
    int jw = jT * 4 + (tid >> 6);
    if (i >= PRE) return;
    float4 bi = bbs[(size_t)img * PRE + i];
    float ai = areas[img * PRE + i];
    int j0 = (tid >> 6) * 64;
    u64 m = 0;
#pragma unroll 4
    for (int b = 0; b < 64; ++b) {
        int j = jw * 64 + b;
        if (j >= PRE) break;
        if (j > i) {
            float4 bj = jb[j0 + b];
            float xx1 = fmaxf(bi.x, bj.x), yy1 = fmaxf(bi.y, bj.y);
            float xx2 = fminf(bi.z, bj.z), yy2 = fminf(bi.w, bj.w);
            float iw = fmaxf(xx2 - xx1, 0.f), ih2 = fmaxf(yy2 - yy1, 0.f);
            float inter = iw * ih2;
            float iou = inter / (ai + ja[j0 + b] - inter + 1e-9f);
            if (iou > 0.7f) m |= (1ull << b);
        }
    }
    mask[((size_t)img * PRE + i) * MWORDS + jw] = m;
}

// ---------------- kernel: sequential NMS scan (early-exit at 300 keeps) ----------
__global__ __launch_bounds__(64) void k_scan(
    const float* __restrict__ sb, const float4* __restrict__ bbs,
    const u64* __restrict__ mask, float* __restrict__ out2)
{
    int img = blockIdx.x;
    int lane = threadIdx.x;
    __shared__ u64 keep[96];
    __shared__ int list[POST];
    for (int w = lane; w < 96; w += 64) {
        u64 bits = 0;
        if (w < 94) {
            for (int b = 0; b < 64; ++b) {
                int j = w * 64 + b;
                if (j < PRE && isfinite(sb[img * PRE + j])) bits |= (1ull << b);
            }
        }
        keep[w] = bits;
    }
    __syncthreads();
    int n = 0;
    for (int w = 0; w < 94 && n < POST; ++w) {
        u64 cur = keep[w];
        while (cur) {
            int b = __builtin_ctzll(cur);
            int i = w * 64 + b;
            if (lane == 0) list[n] = i;
            n++;
            if (n >= POST) break;
            const u64* mrow = mask + ((size_t)img * PRE + i) * MWORDS;
            if (lane < 47) {
                ulonglong2 mv = *(const ulonglong2*)&mrow[2 * lane];
                keep[2 * lane]     &= ~mv.x;
                keep[2 * lane + 1] &= ~mv.y;
            }
            __syncthreads();
            u64 kw = keep[w];
            cur = (b >= 63) ? 0ull : ((kw >> (b + 1)) << (b + 1));
            __syncthreads();
        }
    }
    __syncthreads();
    for (int e = lane; e < POST; e += 64) {
        float4 bx = (e < n) ? bbs[(size_t)img * PRE + list[e]] : make_float4(0, 0, 0, 0);
        *(float4*)&out2[((size_t)img * POST + e) * 4] = bx;
    }
}

extern "C" void kernel_launch(void* const* d_in, const int* in_sizes, int n_in,
                              void* d_out, int out_size, void* d_ws, size_t ws_size,
                              hipStream_t stream)
{
    const float* x     = (const float*)d_in[0];
    const float* w1    = (const float*)d_in[1];
    const float* b1    = (const float*)d_in[2];
    const float* sw    = (const float*)d_in[3];
    const float* sbias = (const float*)d_in[4];
    const float* lw    = (const float*)d_in[5];
    const float* lb    = (const float*)d_in[6];
    const int*   imh   = (const int*)d_in[7];
    const int*   imw   = (const int*)d_in[8];
    float* out = (float*)d_out;
    char* ws = (char*)d_ws;

    _Float16* wh2W = (_Float16*)(ws + 0);
    _Float16* wl2W = (_Float16*)(ws + 65536);
    _Float16* whW  = (_Float16*)(ws + 131072);
    _Float16* wlW  = (_Float16*)(ws + 4849664);
    _Float16* xhW  = (_Float16*)(ws + 9568256);
    _Float16* xlW  = (_Float16*)(ws + 25133056);
    float*    OW      = (float*)(ws + 9568256);     // overlays xh (dead after conv)
    float*    boxesW  = (float*)(ws + 17350656);
    float*    scoresW = (float*)(ws + 21728256);
    float*    sbW     = (float*)(ws + 22822656);
    float*    bbsW    = (float*)(ws + 23014656);
    float*    areasW  = (float*)(ws + 23782656);
    _Float16* fhW  = (_Float16*)(ws + 40697856);
    _Float16* flW  = (_Float16*)(ws + 71827456);
    u64*      maskW   = (u64*)(ws + 40697856);      // overlays fh/fl (dead after hgemm)

    float* out0 = out;            // rpn_locs   (8,34200,4)
    float* out1 = out + 1094400;  // rpn_scores (8,34200,2)
    float* out2 = out + 1641600;  // rois       (2400,4)
    float* out3 = out + 1651200;  // anchors    (34200,4)

    hipLaunchKernelGGL(k_split_w, dim3(512), dim3(256), 0, stream, w1, whW, wlW);
    hipLaunchKernelGGL(k_split_w2, dim3(64), dim3(512), 0, stream, lw, sw, wh2W, wl2W);
    hipLaunchKernelGGL(k_anch, dim3((NA + 255) / 256), dim3(256), 0, stream, out3);
    for (int b = 0; b < 2; ++b) {
        hipLaunchKernelGGL(k_split_x, dim3(119, 16, 4), dim3(32, 8), 0, stream,
                           x + (size_t)b * 4 * CC * PP, xhW, xlW);
        hipLaunchKernelGGL(k_conv, dim3(30, 4, 4), dim3(256), 65536, stream,
                           xhW, xlW, whW, wlW, b1, fhW, flW, b * 4);
    }
    hipLaunchKernelGGL(k_hgemm, dim3(60, NB), dim3(256), 0, stream,
                       fhW, flW, wh2W, wl2W, lb, sbias, OW);
    hipLaunchKernelGGL(k_post, dim3((NB * NA + 255) / 256), dim3(256), 0, stream,
                       OW, imh, imw, out0, out1, boxesW, scoresW);
    hipLaunchKernelGGL(k_select, dim3(NB), dim3(1024), NPAD * 8 + 256 * 4, stream,
                       scoresW, (const float4*)boxesW, sbW, (float4*)bbsW, areasW);
    hipLaunchKernelGGL(k_mask, dim3(94, 24, NB), dim3(256), 0, stream,
                       (const float4*)bbsW, areasW, maskW);
    hipLaunchKernelGGL(k_scan, dim3(NB), dim3(64), 0, stream,
                       sbW, (const float4*)bbsW, maskW, out2);
}